// Round 8
// baseline (384.482 us; speedup 1.0000x reference)
//
#include <hip/hip_runtime.h>
#include <hip/hip_bf16.h>
#include <hip/hip_fp16.h>

#define Hh 160
#define Ww 160
#define Cc 64
#define HWc 25600
#define Bb 4

typedef __attribute__((ext_vector_type(8))) short short8;
typedef __attribute__((ext_vector_type(4))) float f32x4;

__device__ __forceinline__ unsigned short f2bf(float f) {
  unsigned int u = __float_as_uint(f);
  unsigned int r = u + 0x7FFFu + ((u >> 16) & 1u);
  return (unsigned short)(r >> 16);
}
__device__ __forceinline__ float bflo(unsigned int u) {
  return __uint_as_float(u << 16);
}
__device__ __forceinline__ float bfhi(unsigned int u) {
  return __uint_as_float(u & 0xffff0000u);
}

// ---------------------------------------------------------------------------
// Kernel P: role-split prep.
// Blocks [0,400): NCHW f32 -> NHWC bf16 transpose, 256-px tiles, float4 loads.
// Blocks [400,840): weight pre-bake into MFMA A-fragment order.
// ---------------------------------------------------------------------------
__global__ __launch_bounds__(256) void k_prep(
    const float* __restrict__ x, const float* __restrict__ wm,
    const float* __restrict__ wn, const float* __restrict__ ow,
    unsigned short* __restrict__ xT, unsigned short* __restrict__ bf) {
  if (blockIdx.x < 400) {
    __shared__ unsigned short s[64][260];
    int wg = blockIdx.x;  // 400 = 4b * 100
    int b = wg / 100;
    int pix0 = (wg % 100) * 256;
    int l = threadIdx.x & 63, wv = threadIdx.x >> 6;
    const float* xb = x + (size_t)b * Cc * HWc + pix0;
#pragma unroll
    for (int i = 0; i < 16; i++) {
      int c = i * 4 + wv;
      float4 v = *(const float4*)&xb[(size_t)c * HWc + l * 4];
      unsigned int d0 = (unsigned int)f2bf(v.x) | ((unsigned int)f2bf(v.y) << 16);
      unsigned int d1 = (unsigned int)f2bf(v.z) | ((unsigned int)f2bf(v.w) << 16);
      *(uint2*)&s[c][l * 4] = make_uint2(d0, d1);
    }
    __syncthreads();
    int p = threadIdx.x;  // pixel 0..255
    unsigned int w[32];
#pragma unroll
    for (int j = 0; j < 32; j++) {
      unsigned int a = s[2 * j][p];
      unsigned int bb = s[2 * j + 1][p];
      w[j] = a | (bb << 16);
    }
    unsigned short* dst = xT + ((size_t)(b * HWc + pix0 + p)) * 64;
#pragma unroll
    for (int j = 0; j < 8; j++)
      ((uint4*)dst)[j] = make_uint4(w[4 * j], w[4 * j + 1], w[4 * j + 2], w[4 * j + 3]);
  } else {
    int i = (blockIdx.x - 400) * 256 + threadIdx.x;
    if (i < 9 * 2 * 12 * 64 * 8) {
      int j2 = i & 7;
      int lane = (i >> 3) & 63;
      int ntck = i >> 9;
      int nt = ntck % 12;
      int ck = ntck / 12;
      int kk = ck >> 1;
      int chunk = ck & 1;
      int n = nt * 16 + (lane & 15);
      int c = chunk * 32 + (lane >> 4) * 8 + j2;
      float v;
      if (n < 64)
        v = wm[(n * 64 + c) * 9 + kk] + wm[((n + 64) * 64 + c) * 9 + kk];
      else
        v = wn[((n - 64) * 64 + c) * 9 + kk];
      bf[i] = f2bf(v);
    } else if (i < 9 * 2 * 12 * 64 * 8 + 2 * 2 * 64 * 8) {
      int j = i - 9 * 2 * 12 * 64 * 8;
      int j2 = j & 7;
      int lane = (j >> 3) & 63;
      int rest = j >> 9;  // chunk*2 + ntile
      int ntile = rest & 1;
      int chunk = rest >> 1;
      int n = ntile * 16 + (lane & 15);
      int c = chunk * 32 + (lane >> 4) * 8 + j2;
      bf[i] = (n < 18) ? f2bf(ow[n * 64 + c]) : (unsigned short)0;
    }
  }
}

// ---------------------------------------------------------------------------
// gcomb: gather 4 bilinear corners (16B each) and combine into a bf16x8
// B-fragment, fully in registers.
// ---------------------------------------------------------------------------
__device__ __forceinline__ short8 gcomb(const char* __restrict__ gbase, uint4 D,
                                        int off) {
  int bb = (int)D.x + off;
  int dxB = (int)(D.y & 0xffffu);
  int dyB = (int)(D.y >> 16);
  uint4 c00 = *(const uint4*)(gbase + bb);
  uint4 c01 = *(const uint4*)(gbase + bb + dxB);
  uint4 c10 = *(const uint4*)(gbase + bb + dyB);
  uint4 c11 = *(const uint4*)(gbase + bb + dxB + dyB);
  float2 wA = __half22float2(*(const __half2*)&D.z);
  float2 wB = __half22float2(*(const __half2*)&D.w);
  const unsigned int* a = (const unsigned int*)&c00;
  const unsigned int* b = (const unsigned int*)&c01;
  const unsigned int* c = (const unsigned int*)&c10;
  const unsigned int* d = (const unsigned int*)&c11;
  uint4 o;
  unsigned int* op = (unsigned int*)&o;
#pragma unroll
  for (int j = 0; j < 4; j++) {
    float lo = bflo(a[j]) * wA.x + bflo(b[j]) * wA.y + bflo(c[j]) * wB.x +
               bflo(d[j]) * wB.y;
    float hi = bfhi(a[j]) * wA.x + bfhi(b[j]) * wA.y + bfhi(c[j]) * wB.x +
               bfhi(d[j]) * wB.y;
    __hip_bfloat162 hh = __float22bfloat162_rn(make_float2(lo, hi));
    op[j] = *(unsigned int*)&hh;
  }
  return *(short8*)&o;
}

// ---------------------------------------------------------------------------
// Kernel M: one wave per block (64 thr), fully independent: offsets via MFMA,
// per-wave descriptor build, then a BARRIER-FREE k-loop where each lane
// bilinear-gathers its own B-fragment from NHWC xT and feeds 48 MFMAs/kk
// (12 n-tiles x 2 K-chunks x 2 pixel-groups). Weights stream from L1/L2.
// ---------------------------------------------------------------------------
__global__ __launch_bounds__(64, 3) void k_main(
    const unsigned short* __restrict__ xT, const float* __restrict__ w0,
    const float* __restrict__ off_b, const unsigned short* __restrict__ bfrag,
    const unsigned short* __restrict__ obfrag, float* __restrict__ out) {
  __shared__ uint4 gdesc[288];  // [kk][px32]
  __shared__ float2 spy[288];   // [kk][px32]
  const int l = threadIdx.x;    // 0..63
  const int wg = blockIdx.x;    // 3200
  const int band = wg & 7;      // XCD id under round-robin
  const int local = wg >> 3;    // 0..399
  const int b = local / 100;
  const int pix0 = band * 3200 + (local % 100) * 32;
  const int lm = l & 15;
  const int quad = l >> 4;

  const unsigned short* xTb = xT + (size_t)b * HWc * 64;
  const char* gbase = (const char*)xTb;

  f32x4 acc[12][2];
  const f32x4 zero = {0.f, 0.f, 0.f, 0.f};
#pragma unroll
  for (int nt = 0; nt < 12; nt++) {
    acc[nt][0] = zero;
    acc[nt][1] = zero;
  }

  // ---- phase 0: offsets via MFMA for this wave's 2 pixel groups ----
#pragma unroll
  for (int g = 0; g < 2; g++) {
    f32x4 aO0 = zero, aO1 = zero;
    const unsigned short* xrow = xTb + (size_t)(pix0 + g * 16 + lm) * 64;
#pragma unroll
    for (int chunk = 0; chunk < 2; chunk++) {
      short8 sb = *(const short8*)(xrow + chunk * 32 + quad * 8);
      short8 wf0 = *(const short8*)&obfrag[((chunk * 2 + 0) * 64 + l) * 8];
      short8 wf1 = *(const short8*)&obfrag[((chunk * 2 + 1) * 64 + l) * 8];
      aO0 = __builtin_amdgcn_mfma_f32_16x16x32_bf16(wf0, sb, aO0, 0, 0, 0);
      aO1 = __builtin_amdgcn_mfma_f32_16x16x32_bf16(wf1, sb, aO1, 0, 0, 0);
    }
    int pix = pix0 + g * 16 + lm;
    int h = pix / Ww, w = pix % Ww;
    float fh = (float)h, fw = (float)w;
#pragma unroll
    for (int rr = 0; rr < 2; rr++) {
      int n = quad * 4 + 2 * rr;
      int kk = n >> 1;
      float oy = aO0[2 * rr] + off_b[n];
      float ox = aO0[2 * rr + 1] + off_b[n + 1];
      oy = fminf(fmaxf(oy, -fh), 160.0f - fh);
      ox = fminf(fmaxf(ox, -fw), 160.0f - fw);
      if (fabsf(oy) >= 8.0f) oy = 8.0f * tanhf(oy * 0.125f);
      if (fabsf(ox) >= 8.0f) ox = 8.0f * tanhf(ox * 0.125f);
      spy[kk * 32 + g * 16 + lm] =
          make_float2(fh - 1.0f + (float)(kk / 3) + oy,
                      fw - 1.0f + (float)(kk % 3) + ox);
    }
    if (quad == 0) {  // kk=8 from tile1 rows 16,17
      float oy = aO1[0] + off_b[16];
      float ox = aO1[1] + off_b[17];
      oy = fminf(fmaxf(oy, -fh), 160.0f - fh);
      ox = fminf(fmaxf(ox, -fw), 160.0f - fw);
      if (fabsf(oy) >= 8.0f) oy = 8.0f * tanhf(oy * 0.125f);
      if (fabsf(ox) >= 8.0f) ox = 8.0f * tanhf(ox * 0.125f);
      spy[8 * 32 + g * 16 + lm] =
          make_float2(fh + 1.0f + oy, fw + 1.0f + ox);
    }
  }
  __syncthreads();

  // ---- descriptor build: 288 entries over 64 lanes ----
  for (int e = l; e < 288; e += 64) {
    float2 P = spy[e];
    float py = P.x, pxv = P.y;
    float y0f = floorf(py), x0f = floorf(pxv);
    float wy = py - y0f, wx = pxv - x0f;
    int y0 = (int)y0f, x0 = (int)x0f;
    float vy0 = (y0 >= 0 && y0 < Hh) ? 1.f : 0.f;
    float vy1 = (y0 >= -1 && y0 < Hh - 1) ? 1.f : 0.f;
    float vx0 = (x0 >= 0 && x0 < Ww) ? 1.f : 0.f;
    float vx1 = (x0 >= -1 && x0 < Ww - 1) ? 1.f : 0.f;
    int r0 = min(max(y0, 0), Hh - 1);
    int r1 = min(max(y0 + 1, 0), Hh - 1);
    int c0 = min(max(x0, 0), Ww - 1);
    int c1 = min(max(x0 + 1, 0), Ww - 1);
    float w00 = (1.f - wy) * (1.f - wx) * vy0 * vx0;
    float w01 = (1.f - wy) * wx * vy0 * vx1;
    float w10 = wy * (1.f - wx) * vy1 * vx0;
    float w11 = wy * wx * vy1 * vx1;
    uint4 D;
    D.x = (unsigned int)((r0 * Ww + c0) * 128);
    D.y = (unsigned int)((c1 - c0) * 128) |
          ((unsigned int)((r1 - r0) * Ww * 128) << 16);
    __half2 hA = __floats2half2_rn(w00, w01);
    __half2 hB = __floats2half2_rn(w10, w11);
    D.z = *(unsigned int*)&hA;
    D.w = *(unsigned int*)&hB;
    gdesc[e] = D;
  }
  __syncthreads();

  // ---- barrier-free k-loop ----
  for (int kk = 0; kk < 9; kk++) {
    uint4 D0 = gdesc[kk * 32 + lm];       // group 0 pixel
    uint4 D1 = gdesc[kk * 32 + 16 + lm];  // group 1 pixel
    const unsigned short* wbase = bfrag + (size_t)(kk * 2) * 12 * 512;
#pragma unroll
    for (int chunk = 0; chunk < 2; chunk++) {
      const int off = chunk * 64 + quad * 16;
      short8 sfr0 = gcomb(gbase, D0, off);
      short8 sfr1 = gcomb(gbase, D1, off);
      const unsigned short* wck = wbase + (size_t)chunk * 12 * 512 + l * 8;
#pragma unroll
      for (int nt = 0; nt < 12; nt++) {
        short8 wfr = *(const short8*)(wck + nt * 512);
        acc[nt][0] =
            __builtin_amdgcn_mfma_f32_16x16x32_bf16(wfr, sfr0, acc[nt][0], 0, 0, 0);
        acc[nt][1] =
            __builtin_amdgcn_mfma_f32_16x16x32_bf16(wfr, sfr1, acc[nt][1], 0, 0, 0);
      }
    }
  }

  // ---- epilogue: out = (pm + w0) / (1 + |qn0| + |qn1|) ----
  float* ob = out + (size_t)b * Cc * HWc + pix0;
#pragma unroll
  for (int nt = 0; nt < 4; nt++) {
#pragma unroll
    for (int r = 0; r < 4; r++) {
      int oc = nt * 16 + quad * 4 + r;
      float w0v = w0[oc];
#pragma unroll
      for (int g = 0; g < 2; g++) {
        float pm = acc[nt][g][r] + w0v;
        float qn =
            1.0f + fabsf(acc[nt + 4][g][r]) + fabsf(acc[nt + 8][g][r]);
        ob[(size_t)oc * HWc + g * 16 + lm] = pm / qn;
      }
    }
  }
}

extern "C" void kernel_launch(void* const* d_in, const int* in_sizes, int n_in,
                              void* d_out, int out_size, void* d_ws, size_t ws_size,
                              hipStream_t stream) {
  const float* x = (const float*)d_in[0];      // [4,64,160,160]
  const float* off_w = (const float*)d_in[1];  // [18,64]
  const float* off_b = (const float*)d_in[2];  // [18]
  const float* w_m = (const float*)d_in[3];    // [128,64,3,3]
  const float* w_n = (const float*)d_in[4];    // [128,64,3,3]
  const float* w0 = (const float*)d_in[5];     // [64]
  float* out = (float*)d_out;                  // [4,64,160,160]

  // ws layout: bfrag 221184 B | obfrag 4096 B | xT 13107200 B  (~13.3 MB)
  unsigned short* bfrag = (unsigned short*)d_ws;
  unsigned short* obfrag = (unsigned short*)((char*)d_ws + (size_t)221184);
  unsigned short* xT = (unsigned short*)((char*)d_ws + (size_t)225280);

  hipLaunchKernelGGL(k_prep, dim3(840), dim3(256), 0, stream, x, w_m, w_n,
                     off_w, xT, bfrag);
  hipLaunchKernelGGL(k_main, dim3(3200), dim3(64), 0, stream, xT, w0, off_b,
                     bfrag, obfrag, out);
}

// Round 9
// 189.466 us; speedup vs baseline: 2.0293x; 2.0293x over previous
//
#include <hip/hip_runtime.h>
#include <hip/hip_bf16.h>
#include <hip/hip_fp16.h>

#define Hh 160
#define Ww 160
#define Cc 64
#define HWc 25600
#define Bb 4

typedef __attribute__((ext_vector_type(8))) short short8;
typedef __attribute__((ext_vector_type(4))) float f32x4;

__device__ __forceinline__ unsigned short f2bf(float f) {
  unsigned int u = __float_as_uint(f);
  unsigned int r = u + 0x7FFFu + ((u >> 16) & 1u);
  return (unsigned short)(r >> 16);
}
__device__ __forceinline__ float bflo(unsigned int u) {
  return __uint_as_float(u << 16);
}
__device__ __forceinline__ float bfhi(unsigned int u) {
  return __uint_as_float(u & 0xffff0000u);
}

// ---------------------------------------------------------------------------
// Kernel P: role-split prep.
// Blocks [0,400): NCHW f32 -> NHWC bf16 transpose, 256-px tiles, float4 loads.
// Blocks [400,840): weight pre-bake into MFMA A-fragment order.
// ---------------------------------------------------------------------------
__global__ __launch_bounds__(256) void k_prep(
    const float* __restrict__ x, const float* __restrict__ wm,
    const float* __restrict__ wn, const float* __restrict__ ow,
    unsigned short* __restrict__ xT, unsigned short* __restrict__ bf) {
  if (blockIdx.x < 400) {
    __shared__ unsigned short s[64][260];
    int wg = blockIdx.x;  // 400 = 4b * 100
    int b = wg / 100;
    int pix0 = (wg % 100) * 256;
    int l = threadIdx.x & 63, wv = threadIdx.x >> 6;
    const float* xb = x + (size_t)b * Cc * HWc + pix0;
#pragma unroll
    for (int i = 0; i < 16; i++) {
      int c = i * 4 + wv;
      float4 v = *(const float4*)&xb[(size_t)c * HWc + l * 4];
      unsigned int d0 = (unsigned int)f2bf(v.x) | ((unsigned int)f2bf(v.y) << 16);
      unsigned int d1 = (unsigned int)f2bf(v.z) | ((unsigned int)f2bf(v.w) << 16);
      *(uint2*)&s[c][l * 4] = make_uint2(d0, d1);
    }
    __syncthreads();
    int p = threadIdx.x;  // pixel 0..255
    unsigned int w[32];
#pragma unroll
    for (int j = 0; j < 32; j++) {
      unsigned int a = s[2 * j][p];
      unsigned int bb = s[2 * j + 1][p];
      w[j] = a | (bb << 16);
    }
    unsigned short* dst = xT + ((size_t)(b * HWc + pix0 + p)) * 64;
#pragma unroll
    for (int j = 0; j < 8; j++)
      ((uint4*)dst)[j] = make_uint4(w[4 * j], w[4 * j + 1], w[4 * j + 2], w[4 * j + 3]);
  } else {
    int i = (blockIdx.x - 400) * 256 + threadIdx.x;
    if (i < 9 * 2 * 12 * 64 * 8) {
      int j2 = i & 7;
      int lane = (i >> 3) & 63;
      int ntck = i >> 9;
      int nt = ntck % 12;
      int ck = ntck / 12;
      int kk = ck >> 1;
      int chunk = ck & 1;
      int n = nt * 16 + (lane & 15);
      int c = chunk * 32 + (lane >> 4) * 8 + j2;
      float v;
      if (n < 64)
        v = wm[(n * 64 + c) * 9 + kk] + wm[((n + 64) * 64 + c) * 9 + kk];
      else
        v = wn[((n - 64) * 64 + c) * 9 + kk];
      bf[i] = f2bf(v);
    } else if (i < 9 * 2 * 12 * 64 * 8 + 2 * 2 * 64 * 8) {
      int j = i - 9 * 2 * 12 * 64 * 8;
      int j2 = j & 7;
      int lane = (j >> 3) & 63;
      int rest = j >> 9;  // chunk*2 + ntile
      int ntile = rest & 1;
      int chunk = rest >> 1;
      int n = ntile * 16 + (lane & 15);
      int c = chunk * 32 + (lane >> 4) * 8 + j2;
      bf[i] = (n < 18) ? f2bf(ow[n * 64 + c]) : (unsigned short)0;
    }
  }
}

// ---------------------------------------------------------------------------
// gcomb: gather 4 bilinear corners (16B each) and combine into a bf16x8
// B-fragment, fully in registers.
// ---------------------------------------------------------------------------
__device__ __forceinline__ short8 gcomb(const char* __restrict__ gbase, uint4 D,
                                        int off) {
  int bb = (int)D.x + off;
  int dxB = (int)(D.y & 0xffffu);
  int dyB = (int)(D.y >> 16);
  uint4 c00 = *(const uint4*)(gbase + bb);
  uint4 c01 = *(const uint4*)(gbase + bb + dxB);
  uint4 c10 = *(const uint4*)(gbase + bb + dyB);
  uint4 c11 = *(const uint4*)(gbase + bb + dxB + dyB);
  float2 wA = __half22float2(*(const __half2*)&D.z);
  float2 wB = __half22float2(*(const __half2*)&D.w);
  const unsigned int* a = (const unsigned int*)&c00;
  const unsigned int* b = (const unsigned int*)&c01;
  const unsigned int* c = (const unsigned int*)&c10;
  const unsigned int* d = (const unsigned int*)&c11;
  uint4 o;
  unsigned int* op = (unsigned int*)&o;
#pragma unroll
  for (int j = 0; j < 4; j++) {
    float lo = bflo(a[j]) * wA.x + bflo(b[j]) * wA.y + bflo(c[j]) * wB.x +
               bflo(d[j]) * wB.y;
    float hi = bfhi(a[j]) * wA.x + bfhi(b[j]) * wA.y + bfhi(c[j]) * wB.x +
               bfhi(d[j]) * wB.y;
    __hip_bfloat162 hh = __float22bfloat162_rn(make_float2(lo, hi));
    op[j] = *(unsigned int*)&hh;
  }
  return *(short8*)&o;
}

// ---------------------------------------------------------------------------
// Kernel M: one wave per block (64 thr), fully independent: offsets via MFMA,
// per-wave descriptor build, then a BARRIER-FREE k-loop where each lane
// bilinear-gathers its own B-fragment from NHWC xT and feeds 48 MFMAs/kk.
// __launch_bounds__(64,2): 256-reg budget so acc[12][2] (96 AGPRs) + working
// VGPRs fit WITHOUT spill (R8's (64,3) forced a 170-reg cap -> 1.1GB scratch
// traffic; that was the whole regression).
// ---------------------------------------------------------------------------
__global__ __launch_bounds__(64, 2) void k_main(
    const unsigned short* __restrict__ xT, const float* __restrict__ w0,
    const float* __restrict__ off_b, const unsigned short* __restrict__ bfrag,
    const unsigned short* __restrict__ obfrag, float* __restrict__ out) {
  __shared__ uint4 gdesc[288];  // [kk][px32]
  __shared__ float2 spy[288];   // [kk][px32]
  const int l = threadIdx.x;    // 0..63
  const int wg = blockIdx.x;    // 3200
  const int band = wg & 7;      // XCD id under round-robin
  const int local = wg >> 3;    // 0..399
  const int b = local / 100;
  const int pix0 = band * 3200 + (local % 100) * 32;
  const int lm = l & 15;
  const int quad = l >> 4;

  const unsigned short* xTb = xT + (size_t)b * HWc * 64;
  const char* gbase = (const char*)xTb;

  f32x4 acc[12][2];
  const f32x4 zero = {0.f, 0.f, 0.f, 0.f};
#pragma unroll
  for (int nt = 0; nt < 12; nt++) {
    acc[nt][0] = zero;
    acc[nt][1] = zero;
  }

  // ---- phase 0: offsets via MFMA for this wave's 2 pixel groups ----
#pragma unroll
  for (int g = 0; g < 2; g++) {
    f32x4 aO0 = zero, aO1 = zero;
    const unsigned short* xrow = xTb + (size_t)(pix0 + g * 16 + lm) * 64;
#pragma unroll
    for (int chunk = 0; chunk < 2; chunk++) {
      short8 sb = *(const short8*)(xrow + chunk * 32 + quad * 8);
      short8 wf0 = *(const short8*)&obfrag[((chunk * 2 + 0) * 64 + l) * 8];
      short8 wf1 = *(const short8*)&obfrag[((chunk * 2 + 1) * 64 + l) * 8];
      aO0 = __builtin_amdgcn_mfma_f32_16x16x32_bf16(wf0, sb, aO0, 0, 0, 0);
      aO1 = __builtin_amdgcn_mfma_f32_16x16x32_bf16(wf1, sb, aO1, 0, 0, 0);
    }
    int pix = pix0 + g * 16 + lm;
    int h = pix / Ww, w = pix % Ww;
    float fh = (float)h, fw = (float)w;
#pragma unroll
    for (int rr = 0; rr < 2; rr++) {
      int n = quad * 4 + 2 * rr;
      int kk = n >> 1;
      float oy = aO0[2 * rr] + off_b[n];
      float ox = aO0[2 * rr + 1] + off_b[n + 1];
      oy = fminf(fmaxf(oy, -fh), 160.0f - fh);
      ox = fminf(fmaxf(ox, -fw), 160.0f - fw);
      if (fabsf(oy) >= 8.0f) oy = 8.0f * tanhf(oy * 0.125f);
      if (fabsf(ox) >= 8.0f) ox = 8.0f * tanhf(ox * 0.125f);
      spy[kk * 32 + g * 16 + lm] =
          make_float2(fh - 1.0f + (float)(kk / 3) + oy,
                      fw - 1.0f + (float)(kk % 3) + ox);
    }
    if (quad == 0) {  // kk=8 from tile1 rows 16,17
      float oy = aO1[0] + off_b[16];
      float ox = aO1[1] + off_b[17];
      oy = fminf(fmaxf(oy, -fh), 160.0f - fh);
      ox = fminf(fmaxf(ox, -fw), 160.0f - fw);
      if (fabsf(oy) >= 8.0f) oy = 8.0f * tanhf(oy * 0.125f);
      if (fabsf(ox) >= 8.0f) ox = 8.0f * tanhf(ox * 0.125f);
      spy[8 * 32 + g * 16 + lm] =
          make_float2(fh + 1.0f + oy, fw + 1.0f + ox);
    }
  }
  __syncthreads();

  // ---- descriptor build: 288 entries over 64 lanes ----
  for (int e = l; e < 288; e += 64) {
    float2 P = spy[e];
    float py = P.x, pxv = P.y;
    float y0f = floorf(py), x0f = floorf(pxv);
    float wy = py - y0f, wx = pxv - x0f;
    int y0 = (int)y0f, x0 = (int)x0f;
    float vy0 = (y0 >= 0 && y0 < Hh) ? 1.f : 0.f;
    float vy1 = (y0 >= -1 && y0 < Hh - 1) ? 1.f : 0.f;
    float vx0 = (x0 >= 0 && x0 < Ww) ? 1.f : 0.f;
    float vx1 = (x0 >= -1 && x0 < Ww - 1) ? 1.f : 0.f;
    int r0 = min(max(y0, 0), Hh - 1);
    int r1 = min(max(y0 + 1, 0), Hh - 1);
    int c0 = min(max(x0, 0), Ww - 1);
    int c1 = min(max(x0 + 1, 0), Ww - 1);
    float w00 = (1.f - wy) * (1.f - wx) * vy0 * vx0;
    float w01 = (1.f - wy) * wx * vy0 * vx1;
    float w10 = wy * (1.f - wx) * vy1 * vx0;
    float w11 = wy * wx * vy1 * vx1;
    uint4 D;
    D.x = (unsigned int)((r0 * Ww + c0) * 128);
    D.y = (unsigned int)((c1 - c0) * 128) |
          ((unsigned int)((r1 - r0) * Ww * 128) << 16);
    __half2 hA = __floats2half2_rn(w00, w01);
    __half2 hB = __floats2half2_rn(w10, w11);
    D.z = *(unsigned int*)&hA;
    D.w = *(unsigned int*)&hB;
    gdesc[e] = D;
  }
  __syncthreads();

  // ---- barrier-free k-loop ----
  for (int kk = 0; kk < 9; kk++) {
    uint4 D0 = gdesc[kk * 32 + lm];       // group 0 pixel
    uint4 D1 = gdesc[kk * 32 + 16 + lm];  // group 1 pixel
    const unsigned short* wbase = bfrag + (size_t)(kk * 2) * 12 * 512;
#pragma unroll
    for (int chunk = 0; chunk < 2; chunk++) {
      const int off = chunk * 64 + quad * 16;
      short8 sfr0 = gcomb(gbase, D0, off);
      short8 sfr1 = gcomb(gbase, D1, off);
      const unsigned short* wck = wbase + (size_t)chunk * 12 * 512 + l * 8;
#pragma unroll
      for (int nt = 0; nt < 12; nt++) {
        short8 wfr = *(const short8*)(wck + nt * 512);
        acc[nt][0] =
            __builtin_amdgcn_mfma_f32_16x16x32_bf16(wfr, sfr0, acc[nt][0], 0, 0, 0);
        acc[nt][1] =
            __builtin_amdgcn_mfma_f32_16x16x32_bf16(wfr, sfr1, acc[nt][1], 0, 0, 0);
      }
    }
  }

  // ---- epilogue: out = (pm + w0) / (1 + |qn0| + |qn1|) ----
  float* ob = out + (size_t)b * Cc * HWc + pix0;
#pragma unroll
  for (int nt = 0; nt < 4; nt++) {
#pragma unroll
    for (int r = 0; r < 4; r++) {
      int oc = nt * 16 + quad * 4 + r;
      float w0v = w0[oc];
#pragma unroll
      for (int g = 0; g < 2; g++) {
        float pm = acc[nt][g][r] + w0v;
        float qn =
            1.0f + fabsf(acc[nt + 4][g][r]) + fabsf(acc[nt + 8][g][r]);
        ob[(size_t)oc * HWc + g * 16 + lm] = pm / qn;
      }
    }
  }
}

extern "C" void kernel_launch(void* const* d_in, const int* in_sizes, int n_in,
                              void* d_out, int out_size, void* d_ws, size_t ws_size,
                              hipStream_t stream) {
  const float* x = (const float*)d_in[0];      // [4,64,160,160]
  const float* off_w = (const float*)d_in[1];  // [18,64]
  const float* off_b = (const float*)d_in[2];  // [18]
  const float* w_m = (const float*)d_in[3];    // [128,64,3,3]
  const float* w_n = (const float*)d_in[4];    // [128,64,3,3]
  const float* w0 = (const float*)d_in[5];     // [64]
  float* out = (float*)d_out;                  // [4,64,160,160]

  // ws layout: bfrag 221184 B | obfrag 4096 B | xT 13107200 B  (~13.3 MB)
  unsigned short* bfrag = (unsigned short*)d_ws;
  unsigned short* obfrag = (unsigned short*)((char*)d_ws + (size_t)221184);
  unsigned short* xT = (unsigned short*)((char*)d_ws + (size_t)225280);

  hipLaunchKernelGGL(k_prep, dim3(840), dim3(256), 0, stream, x, w_m, w_n,
                     off_w, xT, bfrag);
  hipLaunchKernelGGL(k_main, dim3(3200), dim3(64), 0, stream, xT, w0, off_b,
                     bfrag, obfrag, out);
}

// Round 10
// 126.593 us; speedup vs baseline: 3.0371x; 1.4967x over previous
//
#include <hip/hip_runtime.h>
#include <hip/hip_bf16.h>
#include <hip/hip_fp16.h>

#define Hh 160
#define Ww 160
#define Cc 64
#define HWc 25600
#define Bb 4
#define AST 76  // A-tile row stride in halves (152B): 2-way banks on b128 reads

typedef __attribute__((ext_vector_type(8))) _Float16 half8;
typedef __attribute__((ext_vector_type(4))) float f32x4;

__device__ __forceinline__ unsigned int f2h2u(float a, float b) {
  __half2 h = __floats2half2_rn(a, b);
  return *(unsigned int*)&h;
}

// ---------------------------------------------------------------------------
// Kernel P: role-split prep.
// Blocks [0,400): NCHW f32 -> NHWC f16 transpose, 256-px tiles, float4 loads.
// Blocks [400,840): weight pre-bake (f16) into MFMA A-fragment order.
// ---------------------------------------------------------------------------
__global__ __launch_bounds__(256) void k_prep(
    const float* __restrict__ x, const float* __restrict__ wm,
    const float* __restrict__ wn, const float* __restrict__ ow,
    unsigned short* __restrict__ xT, unsigned short* __restrict__ bf) {
  if (blockIdx.x < 400) {
    __shared__ unsigned short s[64][260];
    int wg = blockIdx.x;  // 400 = 4b * 100
    int b = wg / 100;
    int pix0 = (wg % 100) * 256;
    int l = threadIdx.x & 63, wv = threadIdx.x >> 6;
    const float* xb = x + (size_t)b * Cc * HWc + pix0;
#pragma unroll
    for (int i = 0; i < 16; i++) {
      int c = i * 4 + wv;
      float4 v = *(const float4*)&xb[(size_t)c * HWc + l * 4];
      *(uint2*)&s[c][l * 4] = make_uint2(f2h2u(v.x, v.y), f2h2u(v.z, v.w));
    }
    __syncthreads();
    int p = threadIdx.x;  // pixel 0..255
    unsigned int w[32];
#pragma unroll
    for (int j = 0; j < 32; j++) {
      unsigned int a = s[2 * j][p];
      unsigned int bb = s[2 * j + 1][p];
      w[j] = (a & 0xffffu) | (bb << 16);
    }
    unsigned short* dst = xT + ((size_t)(b * HWc + pix0 + p)) * 64;
#pragma unroll
    for (int j = 0; j < 8; j++)
      ((uint4*)dst)[j] = make_uint4(w[4 * j], w[4 * j + 1], w[4 * j + 2], w[4 * j + 3]);
  } else {
    int i = (blockIdx.x - 400) * 256 + threadIdx.x;
    if (i < 9 * 2 * 12 * 64 * 8) {
      int j2 = i & 7;
      int lane = (i >> 3) & 63;
      int ntck = i >> 9;
      int nt = ntck % 12;
      int ck = ntck / 12;
      int kk = ck >> 1;
      int chunk = ck & 1;
      int n = nt * 16 + (lane & 15);
      int c = chunk * 32 + (lane >> 4) * 8 + j2;
      float v;
      if (n < 64)
        v = wm[(n * 64 + c) * 9 + kk] + wm[((n + 64) * 64 + c) * 9 + kk];
      else
        v = wn[((n - 64) * 64 + c) * 9 + kk];
      __half hv = __float2half_rn(v);
      bf[i] = *(unsigned short*)&hv;
    } else if (i < 9 * 2 * 12 * 64 * 8 + 2 * 2 * 64 * 8) {
      int j = i - 9 * 2 * 12 * 64 * 8;
      int j2 = j & 7;
      int lane = (j >> 3) & 63;
      int rest = j >> 9;  // chunk*2 + ntile
      int ntile = rest & 1;
      int chunk = rest >> 1;
      int n = ntile * 16 + (lane & 15);
      int c = chunk * 32 + (lane >> 4) * 8 + j2;
      if (n < 18) {
        __half hv = __float2half_rn(ow[n * 64 + c]);
        bf[i] = *(unsigned short*)&hv;
      } else {
        bf[i] = 0;
      }
    }
  }
}

// ---------------------------------------------------------------------------
// Kernel M: fused offset-MFMA + descriptor build + gather + MFMA + epilogue.
// R7 structure (LDS-staged samples, nt-split waves, gathers pipelined one kk
// ahead of the MFMA phase) with the whole sample path in f16: combine is
// 4x __hfma2 per dword (packed, no unpack/pack), MFMA 16x16x32_f16.
// ---------------------------------------------------------------------------
__device__ __forceinline__ void gather2h(const char* __restrict__ gbase, uint4 D,
                                         int chB, uint4& c00, uint4& c01,
                                         uint4& c10, uint4& c11, __half2& W00,
                                         __half2& W01, __half2& W10,
                                         __half2& W11) {
  int bb = (int)D.x + chB;
  int dxB = (int)(D.y & 0xffffu);
  int dyB = (int)(D.y >> 16);
  c00 = *(const uint4*)(gbase + bb);
  c01 = *(const uint4*)(gbase + bb + dxB);
  c10 = *(const uint4*)(gbase + bb + dyB);
  c11 = *(const uint4*)(gbase + bb + dxB + dyB);
  __half2 wz = *(const __half2*)&D.z;
  __half2 ww = *(const __half2*)&D.w;
  W00 = __half2half2(__low2half(wz));
  W01 = __half2half2(__high2half(wz));
  W10 = __half2half2(__low2half(ww));
  W11 = __half2half2(__high2half(ww));
}

__device__ __forceinline__ void combine_write(unsigned short* Arow,
                                              const uint4& c00, const uint4& c01,
                                              const uint4& c10, const uint4& c11,
                                              __half2 W00, __half2 W01,
                                              __half2 W10, __half2 W11) {
  const unsigned int* a = (const unsigned int*)&c00;
  const unsigned int* b = (const unsigned int*)&c01;
  const unsigned int* c = (const unsigned int*)&c10;
  const unsigned int* d = (const unsigned int*)&c11;
  unsigned int o[4];
#pragma unroll
  for (int j = 0; j < 4; j++) {
    __half2 ha = *(const __half2*)&a[j];
    __half2 hb = *(const __half2*)&b[j];
    __half2 hc = *(const __half2*)&c[j];
    __half2 hd = *(const __half2*)&d[j];
    __half2 r = __hfma2(ha, W00,
                        __hfma2(hb, W01, __hfma2(hc, W10, __hmul2(hd, W11))));
    o[j] = *(unsigned int*)&r;
  }
  *(uint4*)Arow = make_uint4(o[0], o[1], o[2], o[3]);
}

__global__ __launch_bounds__(256, 4) void k_main(
    const unsigned short* __restrict__ xT, const float* __restrict__ w0,
    const float* __restrict__ off_b, const unsigned short* __restrict__ bfrag,
    const unsigned short* __restrict__ obfrag, float* __restrict__ out) {
  __shared__ unsigned short A[2][64 * AST];  // [buf][px][c], f16
  __shared__ uint4 gdesc[576];               // per (kk,px) gather descriptor
  float2* spy = (float2*)&A[0][0];           // overlay, dead after desc build
  const int tid = threadIdx.x;
  const int wg = blockIdx.x;  // 1600
  const int band = wg & 7;    // XCD id under round-robin
  const int local = wg >> 3;  // 0..199
  const int b = local / 50;
  const int pix0 = band * 3200 + (local % 50) * 64;
  const int wv = tid >> 6;
  const int l = tid & 63;
  const int lm = l & 15;
  const int quad = l >> 4;
  const int ch8 = l & 7;  // channel octet (16 B)
  const int pr = l >> 3;  // pixel-in-batch 0..7
  const int chB = ch8 * 16;

  const unsigned short* xTb = xT + (size_t)b * HWc * 64;
  const char* gbase = (const char*)xTb;

  f32x4 acc[3][4];
  const f32x4 zero = {0.f, 0.f, 0.f, 0.f};
#pragma unroll
  for (int j = 0; j < 3; j++)
#pragma unroll
    for (int pt = 0; pt < 4; pt++) acc[j][pt] = zero;

  // ---- phase 0: offsets via MFMA -> spy (overlay) ----
  {
    f32x4 aO0 = zero, aO1 = zero;
    const unsigned short* xrow = xTb + (size_t)(pix0 + wv * 16 + lm) * 64;
#pragma unroll
    for (int chunk = 0; chunk < 2; chunk++) {
      half8 sb = *(const half8*)(xrow + chunk * 32 + quad * 8);
      half8 wf0 = *(const half8*)&obfrag[((chunk * 2 + 0) * 64 + l) * 8];
      half8 wf1 = *(const half8*)&obfrag[((chunk * 2 + 1) * 64 + l) * 8];
      aO0 = __builtin_amdgcn_mfma_f32_16x16x32_f16(wf0, sb, aO0, 0, 0, 0);
      aO1 = __builtin_amdgcn_mfma_f32_16x16x32_f16(wf1, sb, aO1, 0, 0, 0);
    }
    int pix = pix0 + wv * 16 + lm;
    int h = pix / Ww, w = pix % Ww;
    float fh = (float)h, fw = (float)w;
#pragma unroll
    for (int rr = 0; rr < 2; rr++) {
      int n = quad * 4 + 2 * rr;
      int kk = n >> 1;
      float oy = aO0[2 * rr] + off_b[n];
      float ox = aO0[2 * rr + 1] + off_b[n + 1];
      oy = fminf(fmaxf(oy, -fh), 160.0f - fh);
      ox = fminf(fmaxf(ox, -fw), 160.0f - fw);
      if (fabsf(oy) >= 8.0f) oy = 8.0f * tanhf(oy * 0.125f);
      if (fabsf(ox) >= 8.0f) ox = 8.0f * tanhf(ox * 0.125f);
      spy[kk * 64 + wv * 16 + lm] =
          make_float2(fh - 1.0f + (float)(kk / 3) + oy,
                      fw - 1.0f + (float)(kk % 3) + ox);
    }
    if (quad == 0) {  // kk=8 from tile1 rows 16,17
      float oy = aO1[0] + off_b[16];
      float ox = aO1[1] + off_b[17];
      oy = fminf(fmaxf(oy, -fh), 160.0f - fh);
      ox = fminf(fmaxf(ox, -fw), 160.0f - fw);
      if (fabsf(oy) >= 8.0f) oy = 8.0f * tanhf(oy * 0.125f);
      if (fabsf(ox) >= 8.0f) ox = 8.0f * tanhf(ox * 0.125f);
      spy[8 * 64 + wv * 16 + lm] =
          make_float2(fh + 1.0f + oy, fw + 1.0f + ox);
    }
  }
  __syncthreads();

  // ---- descriptor build: 576 entries over 256 threads ----
  for (int e = tid; e < 576; e += 256) {
    float2 P = spy[e];
    float py = P.x, pxv = P.y;
    float y0f = floorf(py), x0f = floorf(pxv);
    float wy = py - y0f, wx = pxv - x0f;
    int y0 = (int)y0f, x0 = (int)x0f;
    float vy0 = (y0 >= 0 && y0 < Hh) ? 1.f : 0.f;
    float vy1 = (y0 >= -1 && y0 < Hh - 1) ? 1.f : 0.f;
    float vx0 = (x0 >= 0 && x0 < Ww) ? 1.f : 0.f;
    float vx1 = (x0 >= -1 && x0 < Ww - 1) ? 1.f : 0.f;
    int r0 = min(max(y0, 0), Hh - 1);
    int r1 = min(max(y0 + 1, 0), Hh - 1);
    int c0 = min(max(x0, 0), Ww - 1);
    int c1 = min(max(x0 + 1, 0), Ww - 1);
    float w00 = (1.f - wy) * (1.f - wx) * vy0 * vx0;
    float w01 = (1.f - wy) * wx * vy0 * vx1;
    float w10 = wy * (1.f - wx) * vy1 * vx0;
    float w11 = wy * wx * vy1 * vx1;
    uint4 D;
    D.x = (unsigned int)((r0 * Ww + c0) * 128);
    D.y = (unsigned int)((c1 - c0) * 128) |
          ((unsigned int)((r1 - r0) * Ww * 128) << 16);
    D.z = f2h2u(w00, w01);
    D.w = f2h2u(w10, w11);
    gdesc[e] = D;
  }
  __syncthreads();

  // ---- prologue: gather kk=0 into buf 0 ----
#pragma unroll
  for (int i = 0; i < 2; i++) {
    int pl = wv * 16 + i * 8 + pr;
    uint4 c00, c01, c10, c11;
    __half2 W00, W01, W10, W11;
    gather2h(gbase, gdesc[pl], chB, c00, c01, c10, c11, W00, W01, W10, W11);
    combine_write(&A[0][pl * AST + ch8 * 8], c00, c01, c10, c11, W00, W01, W10,
                  W11);
  }
  __syncthreads();

  for (int kk = 0; kk < 9; kk++) {
    const int cur = kk & 1;
    uint4 g00[2], g01[2], g10[2], g11[2];
    __half2 W00[2], W01[2], W10[2], W11[2];
    if (kk < 8) {  // issue next-kk gathers; latency hides behind MFMA phase
#pragma unroll
      for (int i = 0; i < 2; i++) {
        int pl = wv * 16 + i * 8 + pr;
        gather2h(gbase, gdesc[(kk + 1) * 64 + pl], chB, g00[i], g01[i], g10[i],
                 g11[i], W00[i], W01[i], W10[i], W11[i]);
      }
    }
    // MFMA on current buffer
#pragma unroll
    for (int chunk = 0; chunk < 2; chunk++) {
      half8 sfr[4];
#pragma unroll
      for (int pt = 0; pt < 4; pt++)
        sfr[pt] = *(const half8*)&A[cur][(pt * 16 + lm) * AST + chunk * 32 +
                                         quad * 8];
      half8 wfr[3];
#pragma unroll
      for (int j = 0; j < 3; j++) {
        int nt = j * 4 + wv;
        wfr[j] = *(const half8*)&bfrag[((size_t)((kk * 2 + chunk) * 12 + nt) *
                                           64 + l) * 8];
      }
#pragma unroll
      for (int j = 0; j < 3; j++)
#pragma unroll
        for (int pt = 0; pt < 4; pt++)
          acc[j][pt] = __builtin_amdgcn_mfma_f32_16x16x32_f16(
              wfr[j], sfr[pt], acc[j][pt], 0, 0, 0);
    }
    if (kk < 8) {
#pragma unroll
      for (int i = 0; i < 2; i++) {
        int pl = wv * 16 + i * 8 + pr;
        combine_write(&A[cur ^ 1][pl * AST + ch8 * 8], g00[i], g01[i], g10[i],
                      g11[i], W00[i], W01[i], W10[i], W11[i]);
      }
    }
    __syncthreads();
  }

  // ---- epilogue: out = (pm + w0) / (1 + |qn0| + |qn1|) ----
  float w0v[4];
#pragma unroll
  for (int r = 0; r < 4; r++) w0v[r] = w0[wv * 16 + quad * 4 + r];
  float* ob = out + (size_t)b * Cc * HWc + pix0;
#pragma unroll
  for (int pt = 0; pt < 4; pt++) {
#pragma unroll
    for (int r = 0; r < 4; r++) {
      int oc = wv * 16 + quad * 4 + r;
      float pm = acc[0][pt][r] + w0v[r];
      float qn = 1.0f + fabsf(acc[1][pt][r]) + fabsf(acc[2][pt][r]);
      ob[oc * HWc + pt * 16 + lm] = pm / qn;
    }
  }
}

extern "C" void kernel_launch(void* const* d_in, const int* in_sizes, int n_in,
                              void* d_out, int out_size, void* d_ws, size_t ws_size,
                              hipStream_t stream) {
  const float* x = (const float*)d_in[0];      // [4,64,160,160]
  const float* off_w = (const float*)d_in[1];  // [18,64]
  const float* off_b = (const float*)d_in[2];  // [18]
  const float* w_m = (const float*)d_in[3];    // [128,64,3,3]
  const float* w_n = (const float*)d_in[4];    // [128,64,3,3]
  const float* w0 = (const float*)d_in[5];     // [64]
  float* out = (float*)d_out;                  // [4,64,160,160]

  // ws layout: bfrag 221184 B | obfrag 4096 B | xT 13107200 B  (~13.3 MB)
  unsigned short* bfrag = (unsigned short*)d_ws;
  unsigned short* obfrag = (unsigned short*)((char*)d_ws + (size_t)221184);
  unsigned short* xT = (unsigned short*)((char*)d_ws + (size_t)225280);

  hipLaunchKernelGGL(k_prep, dim3(840), dim3(256), 0, stream, x, w_m, w_n,
                     off_w, xT, bfrag);
  hipLaunchKernelGGL(k_main, dim3(1600), dim3(256), 0, stream, xT, w0, off_b,
                     bfrag, obfrag, out);
}